// Round 14
// baseline (217.621 us; speedup 1.0000x reference)
//
#include <hip/hip_runtime.h>
#include <hip/hip_bf16.h>
#include <hip/hip_cooperative_groups.h>
#include <math.h>

namespace cg = cooperative_groups;

// Problem constants: T=4096, B=64, D=64, SCALE = 1/8.
#define T_DIM 4096
#define B_DIM 64
#define NROWS (T_DIM * B_DIM)   // 262144 rows (r = t*64+b), 64 floats each
#define NTILES (NROWS / 16)     // 16384 16-row MFMA tiles
#define NBLK 256                // coop grid: 1 block/CU guaranteed resident
#define TPW 16                  // tiles per wave (16384 / (256*4))

// Workspace layout (float offsets)
#define WS_MFRAG 0        // 4096 u16 (2048 f): M fragment-linear bf16
#define WS_VFRAG 2048     // 4096 u16: Wv fragment-linear bf16
#define WS_U     4096     // 64 f32: u[k] = sum_o bq[o]*Wk[o,k]
#define WS_W     4160     // 64 f32: w[d] = sum_o Wq[o,d]*bk[o]
#define WS_C     4224     // 1 f32:  c = bq.bk
#define WS_MX    4240     // 64 f32 per-b max
#define WS_INV   4304     // 64 f32 per-b 1/sum
#define WS_SCORE 16384    // [NROWS] scores, natural r order

typedef __attribute__((ext_vector_type(4))) float f32x4;
typedef __attribute__((ext_vector_type(8))) short bf16x8;

static __device__ inline short f2bf(float x) {
  __hip_bfloat16 h = __float2bfloat16(x);
  return *reinterpret_cast<short*>(&h);
}

static __device__ inline bf16x8 cvt8(const float4 a, const float4 b) {
  bf16x8 r;
  r[0] = f2bf(a.x); r[1] = f2bf(a.y); r[2] = f2bf(a.z); r[3] = f2bf(a.w);
  r[4] = f2bf(b.x); r[5] = f2bf(b.y); r[6] = f2bf(b.z); r[7] = f2bf(b.w);
  return r;
}

static __device__ inline float dot4(const float4 a, const float4 b, float acc) {
  acc = fmaf(a.x, b.x, acc); acc = fmaf(a.y, b.y, acc);
  acc = fmaf(a.z, b.z, acc); acc = fmaf(a.w, b.w, acc);
  return acc;
}

// Fragment-linear index (u16 units) for weight element W[d][k].
static __device__ __host__ inline int frag_idx(int d, int k) {
  return ((d >> 4) * 2 + (k >> 5)) * 512 +
         ((((k >> 3) & 3) * 16 + (d & 15)) * 8) + (k & 7);
}

// 16B/lane global->LDS staging (no VGPR dest: cannot be serialized by RA).
static __device__ inline void gll16(const float* src, float* ldsbase) {
  __builtin_amdgcn_global_load_lds(
      (const __attribute__((address_space(1))) unsigned int*)src,
      (__attribute__((address_space(3))) unsigned int*)ldsbase, 16, 0, 0);
}

// ---------------------------------------------------------------------------
// K1: bilinear constants; M and Wv bf16 fragment-linear; u,w,c f32.
__global__ __launch_bounds__(64) void k1_precompute(
    const float* __restrict__ Wq, const float* __restrict__ bq,
    const float* __restrict__ Wk, const float* __restrict__ bk,
    const float* __restrict__ Wv, float* __restrict__ ws) {
  const int tid = threadIdx.x;
  const int blk = blockIdx.x;
  unsigned short* __restrict__ mfrag = (unsigned short*)(ws + WS_MFRAG);
  unsigned short* __restrict__ vfrag = (unsigned short*)(ws + WS_VFRAG);
  if (blk < 64) {
    const int d = blk;
    float acc = 0.f;
#pragma unroll
    for (int o = 0; o < 64; ++o)
      acc = fmaf(Wq[o * 64 + d], Wk[o * 64 + tid], acc);
    const int idx = frag_idx(d, tid);
    mfrag[idx] = (unsigned short)f2bf(acc);
    vfrag[idx] = (unsigned short)f2bf(Wv[d * 64 + tid]);
  } else {
    float uacc = 0.f, wacc = 0.f, cacc = 0.f;
#pragma unroll
    for (int o = 0; o < 64; ++o) {
      uacc = fmaf(bq[o], Wk[o * 64 + tid], uacc);
      wacc = fmaf(Wq[o * 64 + tid], bk[o], wacc);
      cacc = fmaf(bq[o], bk[o], cacc);
    }
    ws[WS_U + tid] = uacc;
    ws[WS_W + tid] = wacc;
    if (tid == 0) ws[WS_C] = cacc;
  }
}

// ---------------------------------------------------------------------------
// Fused phases (bodies = verified R10 K2/K4 macros).

#define P1_STAGE(b_, t_)                                                      \
  {                                                                           \
    const size_t rb_ = (size_t)(t_) * 16;                                     \
    float* Lb_ = &stg[wv][b_][0];                                             \
    _Pragma("unroll") for (int q = 0; q < 4; ++q)                             \
        gll16(fnirs + (rb_ + (lane & 15)) * 64 + (q * 4 + (lane >> 4)) * 4,   \
              Lb_ + q * 256);                                                 \
    _Pragma("unroll") for (int q = 0; q < 4; ++q)                             \
        gll16(eeg + (rb_ + (lane & 15)) * 64 + (q * 4 + (lane >> 4)) * 4,     \
              Lb_ + 1024 + q * 256);                                          \
  }

#define P1_COMP(b_, t_)                                                       \
  {                                                                           \
    const float* LF_ = &stg[wv][b_][0];                                       \
    const float* LE_ = &stg[wv][b_][1024];                                    \
    const float4 f0a_ = *reinterpret_cast<const float4*>(LF_ + (2 * g) * 64 + c * 4); \
    const float4 f0b_ = *reinterpret_cast<const float4*>(LF_ + (2 * g + 1) * 64 + c * 4); \
    const float4 f1a_ = *reinterpret_cast<const float4*>(LF_ + (8 + 2 * g) * 64 + c * 4); \
    const float4 f1b_ = *reinterpret_cast<const float4*>(LF_ + (9 + 2 * g) * 64 + c * 4); \
    float s_ = dot4(f0a_, u0a, dot4(f0b_, u0b, dot4(f1a_, u1a, dot4(f1b_, u1b, 0.f)))); \
    const bf16x8 a0_ = cvt8(f0a_, f0b_);                                      \
    const bf16x8 a1_ = cvt8(f1a_, f1b_);                                      \
    f32x4 acc_[4];                                                            \
    _Pragma("unroll") for (int dt = 0; dt < 4; ++dt) {                        \
      acc_[dt] = __builtin_amdgcn_mfma_f32_16x16x32_bf16(bm[dt][0], a0_, zero, 0, 0, 0); \
      acc_[dt] = __builtin_amdgcn_mfma_f32_16x16x32_bf16(bm[dt][1], a1_, acc_[dt], 0, 0, 0); \
    }                                                                         \
    _Pragma("unroll") for (int dt = 0; dt < 4; ++dt) {                        \
      const float4 Ed_ = *reinterpret_cast<const float4*>(LE_ + (dt * 4 + g) * 64 + c * 4); \
      float4 h_;                                                              \
      h_.x = acc_[dt][0] + wfr[dt].x; h_.y = acc_[dt][1] + wfr[dt].y;         \
      h_.z = acc_[dt][2] + wfr[dt].z; h_.w = acc_[dt][3] + wfr[dt].w;         \
      s_ = dot4(Ed_, h_, s_);                                                 \
    }                                                                         \
    s_ += __shfl_xor(s_, 16, 64);                                             \
    s_ += __shfl_xor(s_, 32, 64);                                             \
    if (lane < 16) score[(t_) * 16 + lane] = (s_ + cb) * 0.125f;              \
  }

#define P3_STAGE(b_, t_, scv_)                                                \
  {                                                                           \
    const size_t rb_ = (size_t)(t_) * 16;                                     \
    float* Lb_ = &stg[wv][b_][0];                                             \
    _Pragma("unroll") for (int q = 0; q < 4; ++q)                             \
        gll16(fnirs + (rb_ + (lane & 15)) * 64 + (q * 4 + (lane >> 4)) * 4,   \
              Lb_ + q * 256);                                                 \
    _Pragma("unroll") for (int q = 0; q < 4; ++q)                             \
        gll16(eeg + (rb_ + (lane & 15)) * 64 + (q * 4 + (lane >> 4)) * 4,     \
              Lb_ + 1024 + q * 256);                                          \
    scv_ = score[(t_) * 16 + c];                                              \
  }

#define P3_COMP(b_, t_, scv_)                                                 \
  {                                                                           \
    const float* LF_ = &stg[wv][b_][0];                                       \
    const float* LE_ = &stg[wv][b_][1024];                                    \
    const float4 f0a_ = *reinterpret_cast<const float4*>(LF_ + (2 * g) * 64 + c * 4); \
    const float4 f0b_ = *reinterpret_cast<const float4*>(LF_ + (2 * g + 1) * 64 + c * 4); \
    const float4 f1a_ = *reinterpret_cast<const float4*>(LF_ + (8 + 2 * g) * 64 + c * 4); \
    const float4 f1b_ = *reinterpret_cast<const float4*>(LF_ + (9 + 2 * g) * 64 + c * 4); \
    const bf16x8 a0_ = cvt8(f0a_, f0b_);                                      \
    const bf16x8 a1_ = cvt8(f1a_, f1b_);                                      \
    f32x4 acc_[4];                                                            \
    _Pragma("unroll") for (int dt = 0; dt < 4; ++dt) {                        \
      acc_[dt] = __builtin_amdgcn_mfma_f32_16x16x32_bf16(bm[dt][0], a0_, zero, 0, 0, 0); \
      acc_[dt] = __builtin_amdgcn_mfma_f32_16x16x32_bf16(bm[dt][1], a1_, acc_[dt], 0, 0, 0); \
    }                                                                         \
    const int bl_ = (((t_) * 16) & 63) + c;                                   \
    const float aC_ = __expf((scv_) - mxl[bl_]) * invl[bl_];                  \
    float* ob_ = out + ((size_t)(t_) * 16 + c) * 64;                          \
    _Pragma("unroll") for (int dt = 0; dt < 4; ++dt) {                        \
      const float4 Ed_ = *reinterpret_cast<const float4*>(LE_ + (dt * 4 + g) * 64 + c * 4); \
      float4 o_;                                                              \
      o_.x = fmaf(aC_, acc_[dt][0] + bvf[dt].x, Ed_.x);                       \
      o_.y = fmaf(aC_, acc_[dt][1] + bvf[dt].y, Ed_.y);                       \
      o_.z = fmaf(aC_, acc_[dt][2] + bvf[dt].z, Ed_.z);                       \
      o_.w = fmaf(aC_, acc_[dt][3] + bvf[dt].w, Ed_.w);                       \
      *reinterpret_cast<float4*>(ob_ + dt * 16 + g * 4) = o_;                 \
    }                                                                         \
  }

#define VMWAIT(n)                                                             \
  asm volatile("s_waitcnt vmcnt(" #n ")" ::: "memory");                       \
  __builtin_amdgcn_sched_barrier(0);

// MODE bitmask: 1=scores, 2=softmax, 4=output. 7 = fused w/ grid sync.
template <int MODE>
__global__ __launch_bounds__(256, 2) void fused_all(
    const float* __restrict__ eeg, const float* __restrict__ fnirs,
    float* __restrict__ wsf, const float* __restrict__ bv,
    float* __restrict__ out) {
  __shared__ float stg[4][2][2048];       // 64 KB staging
  __shared__ unsigned short wfrag[4096];  // M (phase1) then Wv (phase3)
  __shared__ float vec64[64];             // w (phase1) then bv (phase3)
  __shared__ float mxl[64], invl[64];
  __shared__ float red[8];

  const int tid = threadIdx.x;
  const int lane = tid & 63;
  const int wv = tid >> 6;
  const int c = lane & 15;
  const int g = lane >> 4;
  float* __restrict__ score = wsf + WS_SCORE;
  const f32x4 zero = {0.f, 0.f, 0.f, 0.f};
  const int t0 = (blockIdx.x * 4 + wv) * TPW;

  // ================= phase 1: scores =================
  if (MODE & 1) {
    {
      const float4* msrc = reinterpret_cast<const float4*>(wsf + WS_MFRAG);
      float4* mdst = reinterpret_cast<float4*>(wfrag);
      mdst[tid] = msrc[tid];
      mdst[tid + 256] = msrc[tid + 256];
      if (tid < 64) vec64[tid] = wsf[WS_W + tid];
    }
    __syncthreads();

    bf16x8 bm[4][2];
#pragma unroll
    for (int dt = 0; dt < 4; ++dt)
#pragma unroll
      for (int kf = 0; kf < 2; ++kf)
        bm[dt][kf] = *reinterpret_cast<const bf16x8*>(
            wfrag + (((dt * 2 + kf) << 9) + lane * 8));
    float4 wfr[4];
#pragma unroll
    for (int dt = 0; dt < 4; ++dt)
      wfr[dt] = *reinterpret_cast<const float4*>(&vec64[dt * 16 + g * 4]);
    const float4 u0a = *reinterpret_cast<const float4*>(wsf + WS_U + g * 8);
    const float4 u0b = *reinterpret_cast<const float4*>(wsf + WS_U + g * 8 + 4);
    const float4 u1a = *reinterpret_cast<const float4*>(wsf + WS_U + 32 + g * 8);
    const float4 u1b = *reinterpret_cast<const float4*>(wsf + WS_U + 36 + g * 8);
    const float cb = wsf[WS_C];

    P1_STAGE(0, t0);
    P1_STAGE(1, t0 + 1);
#pragma unroll
    for (int ii = 0; ii < 7; ++ii) {
      VMWAIT(8);
      P1_COMP(0, t0 + 2 * ii);
      P1_STAGE(0, t0 + 2 * ii + 2);
      VMWAIT(8);
      P1_COMP(1, t0 + 2 * ii + 1);
      P1_STAGE(1, t0 + 2 * ii + 3);
    }
    VMWAIT(8);
    P1_COMP(0, t0 + 14);
    VMWAIT(0);
    P1_COMP(1, t0 + 15);
  }

  if constexpr (MODE == 7) {
    __threadfence();
    cg::this_grid().sync();
  }

  // ================= phase 2: softmax stats (blocks 0..63) =================
  if (MODE & 2) {
    if (blockIdx.x < 64) {
      const int b = blockIdx.x;
      float vals[16];
      float m = -1e30f;
#pragma unroll
      for (int k = 0; k < 16; ++k) {
        vals[k] = score[(size_t)(k * 256 + tid) * 64 + b];
        m = fmaxf(m, vals[k]);
      }
#pragma unroll
      for (int off = 32; off > 0; off >>= 1)
        m = fmaxf(m, __shfl_xor(m, off, 64));
      if ((tid & 63) == 0) red[tid >> 6] = m;
      __syncthreads();
      m = fmaxf(fmaxf(red[0], red[1]), fmaxf(red[2], red[3]));
      float s = 0.f;
#pragma unroll
      for (int k = 0; k < 16; ++k) s += __expf(vals[k] - m);
#pragma unroll
      for (int off = 32; off > 0; off >>= 1)
        s += __shfl_xor(s, off, 64);
      if ((tid & 63) == 0) red[4 + (tid >> 6)] = s;
      __syncthreads();
      if (tid == 0) {
        wsf[WS_MX + b] = m;
        wsf[WS_INV + b] = 1.0f / (red[4] + red[5] + red[6] + red[7]);
      }
    }
  }

  if constexpr (MODE == 7) {
    __threadfence();
    cg::this_grid().sync();
  }

  // ================= phase 3: output =================
  if (MODE & 4) {
    {
      const float4* vsrc = reinterpret_cast<const float4*>(wsf + WS_VFRAG);
      float4* vdst = reinterpret_cast<float4*>(wfrag);
      vdst[tid] = vsrc[tid];
      vdst[tid + 256] = vsrc[tid + 256];
      if (tid < 64) {
        vec64[tid] = bv[tid];
        mxl[tid] = wsf[WS_MX + tid];
        invl[tid] = wsf[WS_INV + tid];
      }
    }
    __syncthreads();

    bf16x8 bm[4][2];
#pragma unroll
    for (int dt = 0; dt < 4; ++dt)
#pragma unroll
      for (int kf = 0; kf < 2; ++kf)
        bm[dt][kf] = *reinterpret_cast<const bf16x8*>(
            wfrag + (((dt * 2 + kf) << 9) + lane * 8));
    float4 bvf[4];
#pragma unroll
    for (int dt = 0; dt < 4; ++dt)
      bvf[dt] = *reinterpret_cast<const float4*>(&vec64[dt * 16 + g * 4]);

    float scA, scB;
    P3_STAGE(0, t0, scA);
    P3_STAGE(1, t0 + 1, scB);
#pragma unroll
    for (int ii = 0; ii < 7; ++ii) {
      VMWAIT(9);
      P3_COMP(0, t0 + 2 * ii, scA);
      P3_STAGE(0, t0 + 2 * ii + 2, scA);
      VMWAIT(9);
      P3_COMP(1, t0 + 2 * ii + 1, scB);
      P3_STAGE(1, t0 + 2 * ii + 3, scB);
    }
    VMWAIT(9);
    P3_COMP(0, t0 + 14, scA);
    VMWAIT(0);
    P3_COMP(1, t0 + 15, scB);
  }
}

// ---------------------------------------------------------------------------
extern "C" void kernel_launch(void* const* d_in, const int* in_sizes, int n_in,
                              void* d_out, int out_size, void* d_ws, size_t ws_size,
                              hipStream_t stream) {
  const float* eeg   = (const float*)d_in[0];
  const float* fnirs = (const float*)d_in[1];
  const float* Wq    = (const float*)d_in[2];
  const float* bq    = (const float*)d_in[3];
  const float* Wk    = (const float*)d_in[4];
  const float* bk    = (const float*)d_in[5];
  const float* Wv    = (const float*)d_in[6];
  const float* bv    = (const float*)d_in[7];
  float* out = (float*)d_out;
  float* ws  = (float*)d_ws;

  k1_precompute<<<65, 64, 0, stream>>>(Wq, bq, Wk, bk, Wv, ws);

  int dev = 0;
  (void)hipGetDevice(&dev);
  int coop = 0;
  (void)hipDeviceGetAttribute(&coop, hipDeviceAttributeCooperativeLaunch, dev);

  hipError_t cerr = hipErrorUnknown;
  if (coop) {
    void* args[] = {(void*)&eeg, (void*)&fnirs, (void*)&ws, (void*)&bv,
                    (void*)&out};
    cerr = hipLaunchCooperativeKernel(
        reinterpret_cast<void*>(&fused_all<7>), dim3(NBLK), dim3(256), args, 0,
        stream);
  }
  if (cerr != hipSuccess) {
    // Deterministic fallback: identical phases as three plain launches.
    fused_all<1><<<NBLK, 256, 0, stream>>>(eeg, fnirs, ws, bv, out);
    fused_all<2><<<64, 256, 0, stream>>>(eeg, fnirs, ws, bv, out);
    fused_all<4><<<NBLK, 256, 0, stream>>>(eeg, fnirs, ws, bv, out);
  }
}

// Round 15
// 66.758 us; speedup vs baseline: 3.2598x; 3.2598x over previous
//
#include <hip/hip_runtime.h>
#include <hip/hip_bf16.h>
#include <math.h>

// Problem constants: T=4096, B=64, D=64, SCALE = 1/8.
#define T_DIM 4096
#define B_DIM 64
#define NROWS (T_DIM * B_DIM)   // 262144 rows (r = t*64+b), 64 floats each
#define NTILES (NROWS / 16)     // 16384 16-row MFMA tiles

// Workspace layout (float offsets)
#define WS_MFRAG 0        // 4096 u16 (2048 f): M fragment-linear bf16
#define WS_VFRAG 2048     // 4096 u16: Wv fragment-linear bf16
#define WS_U     4096     // 64 f32: u[k] = sum_o bq[o]*Wk[o,k]
#define WS_W     4160     // 64 f32: w[d] = sum_o Wq[o,d]*bk[o]
#define WS_C     4224     // 1 f32:  c = bq.bk
#define WS_MX    4240     // 64 f32: per-b max
#define WS_INV   4304     // 64 f32: per-b 1/sum
#define WS_PM    4368     // 64x64 f32: partial max  [ck*64+b]
#define WS_PS    8464     // 64x64 f32: partial sum
#define WS_SCORE 16384    // [NROWS] scores, natural r order

typedef __attribute__((ext_vector_type(4))) float f32x4;
typedef __attribute__((ext_vector_type(8))) short bf16x8;

static __device__ inline short f2bf(float x) {
  __hip_bfloat16 h = __float2bfloat16(x);
  return *reinterpret_cast<short*>(&h);
}

static __device__ inline bf16x8 cvt8(const float4 a, const float4 b) {
  bf16x8 r;
  r[0] = f2bf(a.x); r[1] = f2bf(a.y); r[2] = f2bf(a.z); r[3] = f2bf(a.w);
  r[4] = f2bf(b.x); r[5] = f2bf(b.y); r[6] = f2bf(b.z); r[7] = f2bf(b.w);
  return r;
}

static __device__ inline float dot4(const float4 a, const float4 b, float acc) {
  acc = fmaf(a.x, b.x, acc); acc = fmaf(a.y, b.y, acc);
  acc = fmaf(a.z, b.z, acc); acc = fmaf(a.w, b.w, acc);
  return acc;
}

// Fragment-linear index (u16 units) for weight element W[d][k]:
// frag (dt=d>>4, kf=k>>5) stored as 64 lanes x 8 elems contiguous.
static __device__ __host__ inline int frag_idx(int d, int k) {
  return ((d >> 4) * 2 + (k >> 5)) * 512 +
         ((((k >> 3) & 3) * 16 + (d & 15)) * 8) + (k & 7);
}

// ---------------------------------------------------------------------------
// K1: bilinear constants; M and Wv stored bf16 FRAGMENT-LINEAR (1KB-contig
// per fragment load in k2/k4); u,w,c f32.
__global__ __launch_bounds__(64) void k1_precompute(
    const float* __restrict__ Wq, const float* __restrict__ bq,
    const float* __restrict__ Wk, const float* __restrict__ bk,
    const float* __restrict__ Wv, float* __restrict__ ws) {
  const int tid = threadIdx.x;
  const int blk = blockIdx.x;
  unsigned short* __restrict__ mfrag = (unsigned short*)(ws + WS_MFRAG);
  unsigned short* __restrict__ vfrag = (unsigned short*)(ws + WS_VFRAG);
  if (blk < 64) {
    const int d = blk;
    float acc = 0.f;
#pragma unroll
    for (int o = 0; o < 64; ++o)
      acc = fmaf(Wq[o * 64 + d], Wk[o * 64 + tid], acc);
    const int idx = frag_idx(d, tid);
    mfrag[idx] = (unsigned short)f2bf(acc);
    vfrag[idx] = (unsigned short)f2bf(Wv[d * 64 + tid]);
  } else {
    float uacc = 0.f, wacc = 0.f, cacc = 0.f;
#pragma unroll
    for (int o = 0; o < 64; ++o) {
      uacc = fmaf(bq[o], Wk[o * 64 + tid], uacc);
      wacc = fmaf(Wq[o * 64 + tid], bk[o], wacc);
      cacc = fmaf(bq[o], bk[o], cacc);
    }
    ws[WS_U + tid] = uacc;
    ws[WS_W + tid] = wacc;
    if (tid == 0) ws[WS_C] = cacc;
  }
}

// ---------------------------------------------------------------------------
// K2: score[r] = 0.125*(e^T M f + w.e + u.f + c).
// All global loads contiguous-1KB; F staged through wave-private swizzled
// LDS to fragment layout; Hp staged back to linear for the epilogue.
__global__ __launch_bounds__(256, 2) void k2_score_mfma(
    const float* __restrict__ eeg, const float* __restrict__ fnirs,
    const unsigned short* __restrict__ mfrag, const float* __restrict__ wvec,
    const float* __restrict__ uvec, const float* __restrict__ cvec,
    float* __restrict__ score) {
  __shared__ float lds[4][1024];
  const int tid = threadIdx.x;
  const int lane = tid & 63;
  const int wv = tid >> 6;
  const int tile = blockIdx.x * 4 + wv;
  const int c = lane & 15;
  const int g = lane >> 4;
  const int rbase = tile * 16;
  float* L = lds[wv];

  // ---- global load phase: every load is a contiguous 1KB wave access ----
  const float* Fb = fnirs + (size_t)rbase * 64;
  const float* Eb = eeg + (size_t)rbase * 64;
  float4 Fj[4], Ej[4];
#pragma unroll
  for (int j = 0; j < 4; ++j)
    Fj[j] = *reinterpret_cast<const float4*>(Fb + j * 256 + lane * 4);
#pragma unroll
  for (int j = 0; j < 4; ++j)
    Ej[j] = *reinterpret_cast<const float4*>(Eb + j * 256 + lane * 4);
  bf16x8 bm[4][2];
#pragma unroll
  for (int dt = 0; dt < 4; ++dt)
#pragma unroll
    for (int kf = 0; kf < 2; ++kf)
      bm[dt][kf] = *reinterpret_cast<const bf16x8*>(
          mfrag + (((dt * 2 + kf) << 9) + lane * 8));
  float4 wf[4];
#pragma unroll
  for (int dt = 0; dt < 4; ++dt)
    wf[dt] = *reinterpret_cast<const float4*>(wvec + dt * 16 + g * 4);
  const float4 u4 = *reinterpret_cast<const float4*>(uvec + c * 4);
  const float cb = cvec[0];
  __builtin_amdgcn_sched_barrier(0);

  // u.f partials in linear layout (lane: row j*4+g, d-chunk c*4..+4)
  float uf[4];
#pragma unroll
  for (int j = 0; j < 4; ++j) uf[j] = dot4(Fj[j], u4, 0.f);

  // stage F -> LDS, XOR-swizzled (chunk ^= row&7; chunk = 8 floats)
#pragma unroll
  for (int j = 0; j < 4; ++j) {
    const int r = j * 4 + g;
    const int addr = r * 64 + ((((c >> 1) ^ (r & 7)) << 3) + ((c & 1) << 2));
    *reinterpret_cast<float4*>(&L[addr]) = Fj[j];
  }
  // read F in fragment layout: lane (c,g) row c, k = h*32 + g*8 .. +8
  const int fr0 = c * 64 + (((g) ^ (c & 7)) << 3);
  const int fr1 = c * 64 + (((4 + g) ^ (c & 7)) << 3);
  const float4 p00 = *reinterpret_cast<const float4*>(&L[fr0]);
  const float4 p01 = *reinterpret_cast<const float4*>(&L[fr0 + 4]);
  const float4 p10 = *reinterpret_cast<const float4*>(&L[fr1]);
  const float4 p11 = *reinterpret_cast<const float4*>(&L[fr1 + 4]);
  const bf16x8 a0 = cvt8(p00, p01);
  const bf16x8 a1 = cvt8(p10, p11);

  const f32x4 zero = {0.f, 0.f, 0.f, 0.f};
  f32x4 acc[4];
#pragma unroll
  for (int dt = 0; dt < 4; ++dt) {
    acc[dt] = __builtin_amdgcn_mfma_f32_16x16x32_bf16(bm[dt][0], a0, zero, 0, 0, 0);
    acc[dt] = __builtin_amdgcn_mfma_f32_16x16x32_bf16(bm[dt][1], a1, acc[dt], 0, 0, 0);
  }

  // Hp = acc + w, staged C-layout -> LDS (reuse same slice; in-wave DS order)
#pragma unroll
  for (int dt = 0; dt < 4; ++dt) {
    float4 hp;
    hp.x = acc[dt][0] + wf[dt].x; hp.y = acc[dt][1] + wf[dt].y;
    hp.z = acc[dt][2] + wf[dt].z; hp.w = acc[dt][3] + wf[dt].w;
    const int ch = dt * 2 + (g >> 1);
    const int addr = c * 64 + (((ch ^ (c & 7)) << 3) + ((g & 1) << 2));
    *reinterpret_cast<float4*>(&L[addr]) = hp;
  }
  // linear epilogue: p = E.(Hp) + u.f; reduce over the 16 c-lanes
#pragma unroll
  for (int j = 0; j < 4; ++j) {
    const int r = j * 4 + g;
    const int addr = r * 64 + ((((c >> 1) ^ (r & 7)) << 3) + ((c & 1) << 2));
    const float4 hp = *reinterpret_cast<const float4*>(&L[addr]);
    float p = dot4(Ej[j], hp, uf[j]);
    p += __shfl_xor(p, 1, 64);
    p += __shfl_xor(p, 2, 64);
    p += __shfl_xor(p, 4, 64);
    p += __shfl_xor(p, 8, 64);
    if (c == 0) score[rbase + j * 4 + g] = (p + cb) * 0.125f;
  }
}

// ---------------------------------------------------------------------------
// K3a: per-(64-t-chunk) online (m,s) for ALL b. lane = b -> coalesced reads.
__global__ __launch_bounds__(256) void k3a_partial(
    const float* __restrict__ sc, float* __restrict__ pm,
    float* __restrict__ ps) {
  __shared__ float sm[4][64], ss[4][64];
  const int tid = threadIdx.x;
  const int b = tid & 63;
  const int tq = tid >> 6;
  const int t0 = blockIdx.x * 64;
  float m = -1e30f, s = 0.f;
#pragma unroll
  for (int k = 0; k < 16; ++k) {
    const float v = sc[(size_t)(t0 + k * 4 + tq) * 64 + b];
    const float mn = fmaxf(m, v);
    s = s * __expf(m - mn) + __expf(v - mn);
    m = mn;
  }
  sm[tq][b] = m; ss[tq][b] = s;
  __syncthreads();
  if (tid < 64) {
    float M = sm[0][b], S = ss[0][b];
#pragma unroll
    for (int w = 1; w < 4; ++w) {
      const float m2 = sm[w][b], s2 = ss[w][b];
      const float Mn = fmaxf(M, m2);
      S = S * __expf(M - Mn) + s2 * __expf(m2 - Mn);
      M = Mn;
    }
    pm[blockIdx.x * 64 + b] = M;
    ps[blockIdx.x * 64 + b] = S;
  }
}

// K3b: combine 64 chunk-partials per b. One block.
__global__ __launch_bounds__(64) void k3b_combine(
    const float* __restrict__ pm, const float* __restrict__ ps,
    float* __restrict__ mx, float* __restrict__ inv) {
  const int b = threadIdx.x;
  float M = pm[b], S = ps[b];
#pragma unroll
  for (int ck = 1; ck < 64; ++ck) {
    const float m2 = pm[ck * 64 + b], s2 = ps[ck * 64 + b];
    const float Mn = fmaxf(M, m2);
    S = S * __expf(M - Mn) + s2 * __expf(m2 - Mn);
    M = Mn;
  }
  mx[b] = M;
  inv[b] = 1.0f / S;
}

// ---------------------------------------------------------------------------
// K4: out = eeg + attn*(Wv f + bv). Same staging discipline; stores are
// contiguous 1KB (V staged C-layout -> linear with attn already folded).
__global__ __launch_bounds__(256, 2) void k4_output_mfma(
    const float* __restrict__ eeg, const float* __restrict__ fnirs,
    const unsigned short* __restrict__ vfrag, const float* __restrict__ bv,
    const float* __restrict__ score, const float* __restrict__ mx,
    const float* __restrict__ inv, float* __restrict__ out) {
  __shared__ float lds[4][1024];
  const int tid = threadIdx.x;
  const int lane = tid & 63;
  const int wv = tid >> 6;
  const int tile = blockIdx.x * 4 + wv;
  const int c = lane & 15;
  const int g = lane >> 4;
  const int rbase = tile * 16;
  float* L = lds[wv];

  // ---- global load phase ----
  const float* Fb = fnirs + (size_t)rbase * 64;
  const float* Eb = eeg + (size_t)rbase * 64;
  float4 Fj[4], Ej[4];
#pragma unroll
  for (int j = 0; j < 4; ++j)
    Fj[j] = *reinterpret_cast<const float4*>(Fb + j * 256 + lane * 4);
#pragma unroll
  for (int j = 0; j < 4; ++j)
    Ej[j] = *reinterpret_cast<const float4*>(Eb + j * 256 + lane * 4);
  bf16x8 bm[4][2];
#pragma unroll
  for (int dt = 0; dt < 4; ++dt)
#pragma unroll
    for (int kf = 0; kf < 2; ++kf)
      bm[dt][kf] = *reinterpret_cast<const bf16x8*>(
          vfrag + (((dt * 2 + kf) << 9) + lane * 8));
  float4 bvf[4];
#pragma unroll
  for (int dt = 0; dt < 4; ++dt)
    bvf[dt] = *reinterpret_cast<const float4*>(bv + dt * 16 + g * 4);
  const float scr = score[rbase + c];
  const int bidx = (rbase + c) & 63;
  const float mxv = mx[bidx];
  const float invv = inv[bidx];
  __builtin_amdgcn_sched_barrier(0);

  // stage F -> LDS swizzled
#pragma unroll
  for (int j = 0; j < 4; ++j) {
    const int r = j * 4 + g;
    const int addr = r * 64 + ((((c >> 1) ^ (r & 7)) << 3) + ((c & 1) << 2));
    *reinterpret_cast<float4*>(&L[addr]) = Fj[j];
  }
  const int fr0 = c * 64 + (((g) ^ (c & 7)) << 3);
  const int fr1 = c * 64 + (((4 + g) ^ (c & 7)) << 3);
  const float4 p00 = *reinterpret_cast<const float4*>(&L[fr0]);
  const float4 p01 = *reinterpret_cast<const float4*>(&L[fr0 + 4]);
  const float4 p10 = *reinterpret_cast<const float4*>(&L[fr1]);
  const float4 p11 = *reinterpret_cast<const float4*>(&L[fr1 + 4]);
  const bf16x8 a0 = cvt8(p00, p01);
  const bf16x8 a1 = cvt8(p10, p11);

  const f32x4 zero = {0.f, 0.f, 0.f, 0.f};
  f32x4 acc[4];
#pragma unroll
  for (int dt = 0; dt < 4; ++dt) {
    acc[dt] = __builtin_amdgcn_mfma_f32_16x16x32_bf16(bm[dt][0], a0, zero, 0, 0, 0);
    acc[dt] = __builtin_amdgcn_mfma_f32_16x16x32_bf16(bm[dt][1], a1, acc[dt], 0, 0, 0);
  }

  // attn (per row c), fold into V, stage C-layout -> LDS
  const float aC = __expf(scr - mxv) * invv;
#pragma unroll
  for (int dt = 0; dt < 4; ++dt) {
    float4 v4;
    v4.x = aC * (acc[dt][0] + bvf[dt].x); v4.y = aC * (acc[dt][1] + bvf[dt].y);
    v4.z = aC * (acc[dt][2] + bvf[dt].z); v4.w = aC * (acc[dt][3] + bvf[dt].w);
    const int ch = dt * 2 + (g >> 1);
    const int addr = c * 64 + (((ch ^ (c & 7)) << 3) + ((g & 1) << 2));
    *reinterpret_cast<float4*>(&L[addr]) = v4;
  }
  // linear epilogue: out = E + V (1KB-contiguous stores)
  float* Ob = out + (size_t)rbase * 64;
#pragma unroll
  for (int j = 0; j < 4; ++j) {
    const int r = j * 4 + g;
    const int addr = r * 64 + ((((c >> 1) ^ (r & 7)) << 3) + ((c & 1) << 2));
    const float4 v = *reinterpret_cast<const float4*>(&L[addr]);
    float4 o;
    o.x = Ej[j].x + v.x; o.y = Ej[j].y + v.y;
    o.z = Ej[j].z + v.z; o.w = Ej[j].w + v.w;
    *reinterpret_cast<float4*>(Ob + j * 256 + lane * 4) = o;
  }
}

// ---------------------------------------------------------------------------
extern "C" void kernel_launch(void* const* d_in, const int* in_sizes, int n_in,
                              void* d_out, int out_size, void* d_ws, size_t ws_size,
                              hipStream_t stream) {
  const float* eeg   = (const float*)d_in[0];
  const float* fnirs = (const float*)d_in[1];
  const float* Wq    = (const float*)d_in[2];
  const float* bq    = (const float*)d_in[3];
  const float* Wk    = (const float*)d_in[4];
  const float* bk    = (const float*)d_in[5];
  const float* Wv    = (const float*)d_in[6];
  const float* bv    = (const float*)d_in[7];
  float* out = (float*)d_out;
  float* ws  = (float*)d_ws;

  k1_precompute<<<65, 64, 0, stream>>>(Wq, bq, Wk, bk, Wv, ws);
  k2_score_mfma<<<NTILES / 4, 256, 0, stream>>>(
      eeg, fnirs, (const unsigned short*)(ws + WS_MFRAG), ws + WS_W,
      ws + WS_U, ws + WS_C, ws + WS_SCORE);
  k3a_partial<<<64, 256, 0, stream>>>(ws + WS_SCORE, ws + WS_PM, ws + WS_PS);
  k3b_combine<<<1, 64, 0, stream>>>(ws + WS_PM, ws + WS_PS,
                                    ws + WS_MX, ws + WS_INV);
  k4_output_mfma<<<NTILES / 4, 256, 0, stream>>>(
      eeg, fnirs, (const unsigned short*)(ws + WS_VFRAG), bv,
      ws + WS_SCORE, ws + WS_MX, ws + WS_INV, out);
}